// Round 4
// baseline (344.898 us; speedup 1.0000x reference)
//
#include <hip/hip_runtime.h>
#include <hip/hip_bf16.h>

namespace {

typedef __attribute__((ext_vector_type(8))) short short8;
typedef __attribute__((ext_vector_type(4))) float f32x4;

constexpr int H = 128;
constexpr int N = 200;
constexpr int BN = 1600;          // B*N
constexpr int X_SIZE = BN * H;    // 204800
constexpr int NH = N * H;         // 25600

// ws offsets (floats)
constexpr int WS_VX    = 0;
constexpr int WS_UX    = WS_VX + X_SIZE;
constexpr int WS_VXN   = WS_UX + X_SIZE;
constexpr int WS_XTMP  = WS_VXN + X_SIZE;
constexpr int WS_ESUMS = WS_XTMP + X_SIZE;     // 32 slots x H
constexpr int WS_ESSQS = WS_ESUMS + 32 * H;
constexpr int WS_NSUMS = WS_ESSQS + 32 * H;    // 32 slots x H
constexpr int WS_NSSQS = WS_NSUMS + 32 * H;
constexpr int WS_STAT_END = WS_NSSQS + 32 * H;
constexpr int WS_ESC   = WS_STAT_END;
constexpr int WS_ESH   = WS_ESC + H;
constexpr int WS_NSC   = WS_ESH + H;
constexpr int WS_NSH   = WS_NSC + H;

__device__ __forceinline__ unsigned short f2bf(float f) {
  __hip_bfloat16 h = __float2bfloat16(f);
  return __builtin_bit_cast(unsigned short, h);
}

__device__ __forceinline__ short8 pack8(f32x4 a, f32x4 b) {
  short8 r;
  r[0] = (short)f2bf(a[0]); r[1] = (short)f2bf(a[1]);
  r[2] = (short)f2bf(a[2]); r[3] = (short)f2bf(a[3]);
  r[4] = (short)f2bf(b[0]); r[5] = (short)f2bf(b[1]);
  r[6] = (short)f2bf(b[2]); r[7] = (short)f2bf(b[3]);
  return r;
}

// ---- node linears: Vx, Ux, Vxn (masked) ----
__global__ __launch_bounds__(128) void k_prep(
    const float* __restrict__ x, const int* __restrict__ mask,
    const float* __restrict__ VeW, const float* __restrict__ Veb,
    const float* __restrict__ UnW, const float* __restrict__ Unb,
    const float* __restrict__ VnW, const float* __restrict__ Vnb,
    float* __restrict__ ws) {
  const int bi = blockIdx.x, h = threadIdx.x;
  __shared__ float xr[H];
  xr[h] = x[bi * H + h];
  __syncthreads();
  const float mi = (float)mask[bi];
  float a0 = 0.f, a1 = 0.f, a2 = 0.f;
  #pragma unroll 4
  for (int k = 0; k < H; k += 4) {
    const float x0 = xr[k], x1 = xr[k + 1], x2 = xr[k + 2], x3 = xr[k + 3];
    float4 w;
    w = *(const float4*)&VeW[h * H + k];
    a0 += w.x * x0 + w.y * x1 + w.z * x2 + w.w * x3;
    w = *(const float4*)&UnW[h * H + k];
    a1 += w.x * x0 + w.y * x1 + w.z * x2 + w.w * x3;
    w = *(const float4*)&VnW[h * H + k];
    a2 += w.x * x0 + w.y * x1 + w.z * x2 + w.w * x3;
  }
  ws[WS_VX  + bi * H + h] = mi * (a0 + Veb[h]);
  ws[WS_UX  + bi * H + h] = mi * (a1 + Unb[h]);
  ws[WS_VXN + bi * H + h] = mi * (a2 + Vnb[h]);
}

// ---- pass 0: GEMM (e@Ue^T) + edge stats + sigmoid aggregation + x_tmp/node stats ----
// Block = one (b,i). 4 waves, no in-loop barriers.
// wave w: pair=w>>1 owns j-tiles pair::2; half=w&1 owns h in [64*half, 64*half+64).
// e fragments loaded global->VGPR with one-tile register prefetch.
__global__ __launch_bounds__(256, 3) void k_edge0(
    const float* __restrict__ e, const int* __restrict__ mask,
    const float* __restrict__ UeW, const float* __restrict__ Ueb,
    float* __restrict__ ws) {
  const int bi = blockIdx.x;
  const int b = bi / N;
  const int tid = threadIdx.x;
  const int w = tid >> 6, lane = tid & 63;
  const int l15 = lane & 15, lg = lane >> 4;
  const int half = w & 1, pair = w >> 1;
  const int hbase = half * 64;

  __shared__ float mrow[N];
  __shared__ float pS[4][64], pS2[4][64], pA[4][64];

  if (tid < N) mrow[tid] = (float)mask[b * N + tid];
  __syncthreads();

  const float mi = (float)mask[bi];
  const float* __restrict__ eg = e + (size_t)bi * NH;

  // W frags: lane holds W[hbase+ht*16+l15][s*32 + lg*8 + (0..7)] (bf16, B-operand)
  short8 Wf[4][4];
  #pragma unroll
  for (int ht = 0; ht < 4; ++ht) {
    const float* wr = &UeW[(size_t)(hbase + ht * 16 + l15) * H + lg * 8];
    #pragma unroll
    for (int s = 0; s < 4; ++s) {
      const f32x4 u0 = *(const f32x4*)(wr + s * 32);
      const f32x4 u1 = *(const f32x4*)(wr + s * 32 + 4);
      Wf[ht][s] = pack8(u0, u1);
    }
  }

  float basev[4];
  #pragma unroll
  for (int ht = 0; ht < 4; ++ht) {
    const int h = hbase + ht * 16 + l15;
    basev[ht] = Ueb[h] + ws[WS_VX + (size_t)bi * H + h];
  }

  float bnS[4] = {0.f, 0.f, 0.f, 0.f};
  float bnS2[4] = {0.f, 0.f, 0.f, 0.f};
  float ag[4] = {0.f, 0.f, 0.f, 0.f};

  auto loadraw = [&](int jt, f32x4* dst) {
    const int jl = min(jt * 16 + l15, N - 1);   // clamp tail rows (masked later)
    const float* er = eg + (size_t)jl * H + lg * 8;
    #pragma unroll
    for (int s = 0; s < 4; ++s) {
      dst[2 * s]     = *(const f32x4*)(er + s * 32);
      dst[2 * s + 1] = *(const f32x4*)(er + s * 32 + 4);
    }
  };

  f32x4 raw[8];
  loadraw(pair, raw);

  for (int jt = pair; jt < 13; jt += 2) {
    f32x4 nraw[8];
    if (jt + 2 < 13) loadraw(jt + 2, nraw);   // prefetch stays in flight through MFMA

    short8 Ef[4];
    #pragma unroll
    for (int s = 0; s < 4; ++s) Ef[s] = pack8(raw[2 * s], raw[2 * s + 1]);

    f32x4 acc[4] = {f32x4(0.f), f32x4(0.f), f32x4(0.f), f32x4(0.f)};
    #pragma unroll
    for (int s = 0; s < 4; ++s) {
      #pragma unroll
      for (int ht = 0; ht < 4; ++ht)   // D[j][h]: col h = ht*16+l15, row j = j0+4*lg+r
        acc[ht] = __builtin_amdgcn_mfma_f32_16x16x32_bf16(Ef[s], Wf[ht][s], acc[ht], 0, 0, 0);
    }

    const int j0 = jt * 16;
    #pragma unroll
    for (int r = 0; r < 4; ++r) {
      const int j = j0 + 4 * lg + r;
      const bool valid = (j < N);
      const int jc = valid ? j : N - 1;
      const float msk = valid ? mi * mrow[jc] : 0.f;
      const float* rv = &ws[WS_VX + (size_t)(b * N + jc) * H];
      const float* rn = &ws[WS_VXN + (size_t)(b * N + jc) * H];
      #pragma unroll
      for (int ht = 0; ht < 4; ++ht) {
        const int h = hbase + ht * 16 + l15;
        const float v = acc[ht][r] + basev[ht] + rv[h];
        bnS[ht]  += msk * v;
        bnS2[ht] += msk * v * v;
        const float sg = __builtin_amdgcn_rcpf(1.f + __expf(-v));
        ag[ht] += msk * sg * rn[h];
      }
    }
    #pragma unroll
    for (int k = 0; k < 8; ++k) raw[k] = nraw[k];
  }

  // reduce stats over lg (j-row groups); lanes with same l15 converge
  #pragma unroll
  for (int ht = 0; ht < 4; ++ht) {
    bnS[ht]  += __shfl_xor(bnS[ht], 16);  bnS[ht]  += __shfl_xor(bnS[ht], 32);
    bnS2[ht] += __shfl_xor(bnS2[ht], 16); bnS2[ht] += __shfl_xor(bnS2[ht], 32);
    ag[ht]   += __shfl_xor(ag[ht], 16);   ag[ht]   += __shfl_xor(ag[ht], 32);
  }
  if (lg == 0) {
    #pragma unroll
    for (int ht = 0; ht < 4; ++ht) {
      pS[w][ht * 16 + l15] = bnS[ht];
      pS2[w][ht * 16 + l15] = bnS2[ht];
      pA[w][ht * 16 + l15] = ag[ht];
    }
  }
  __syncthreads();
  if (tid < H) {
    const int hf = tid >> 6, idx = tid & 63;   // waves {hf, hf+2} share this h-half
    const float s1 = pS[hf][idx] + pS[hf + 2][idx];
    const float s2 = pS2[hf][idx] + pS2[hf + 2][idx];
    const float s3 = pA[hf][idx] + pA[hf + 2][idx];
    const int slot = (bi & 31) * H + tid;
    atomicAdd(&ws[WS_ESUMS + slot], s1);
    atomicAdd(&ws[WS_ESSQS + slot], s2);
    // fused x_tmp = Ux + agg, plus node BN partials
    const float v = ws[WS_UX + (size_t)bi * H + tid] + s3;
    ws[WS_XTMP + (size_t)bi * H + tid] = v;
    atomicAdd(&ws[WS_NSUMS + slot], mi * v);
    atomicAdd(&ws[WS_NSSQS + slot], mi * v * v);
  }
}

// ---- counts + finalize BN scale/shift for edge and node ----
__global__ void k_stats(const int* __restrict__ mask,
                        const float* __restrict__ beg, const float* __restrict__ beb,
                        const float* __restrict__ bng, const float* __restrict__ bnb,
                        float* __restrict__ ws) {
  __shared__ float sb[8];
  const int t = threadIdx.x;          // 256 threads
  const int b = t >> 5, li = t & 31;
  float s = 0.f;
  for (int i = li; i < N; i += 32) s += (float)mask[b * N + i];
  #pragma unroll
  for (int o = 16; o >= 1; o >>= 1) s += __shfl_down(s, o, 32);
  if (li == 0) sb[b] = s;
  __syncthreads();
  if (t < H) {
    float cn = 0.f, ce = 0.f;
    #pragma unroll
    for (int bb = 0; bb < 8; ++bb) { cn += sb[bb]; ce += sb[bb] * sb[bb]; }
    ce = fmaxf(ce, 1.f); cn = fmaxf(cn, 1.f);
    float es = 0.f, es2 = 0.f, ns = 0.f, ns2 = 0.f;
    #pragma unroll 4
    for (int k = 0; k < 32; ++k) {
      es  += ws[WS_ESUMS + k * H + t];
      es2 += ws[WS_ESSQS + k * H + t];
      ns  += ws[WS_NSUMS + k * H + t];
      ns2 += ws[WS_NSSQS + k * H + t];
    }
    const float me = es / ce;
    const float ve = fmaxf(es2 / ce - me * me, 0.f);
    const float se = rsqrtf(ve + 1e-5f) * beg[t];
    ws[WS_ESC + t] = se;
    ws[WS_ESH + t] = beb[t] - me * se;
    const float mn = ns / cn;
    const float vn = fmaxf(ns2 / cn - mn * mn, 0.f);
    const float sn = rsqrtf(vn + 1e-5f) * bng[t];
    ws[WS_NSC + t] = sn;
    ws[WS_NSH + t] = bnb[t] - mn * sn;
  }
}

// ---- x_new = x + relu(masked BN(x_tmp)) ----
__global__ void k_x2(const float* __restrict__ x, const int* __restrict__ mask,
                     const float* __restrict__ ws, float* __restrict__ out) {
  const int idx = blockIdx.x * 256 + threadIdx.x;
  if (idx >= X_SIZE) return;
  const int h = idx & 127, bi = idx >> 7;
  const float v = ws[WS_XTMP + idx];
  const float r = (mask[bi] != 0) ? (v * ws[WS_NSC + h] + ws[WS_NSH + h]) : v;
  out[idx] = x[idx] + fmaxf(r, 0.f);
}

// ---- pass 1: recompute e_tmp, normalize + residual + write (swapped MFMA) ----
// Same decomposition as pass 0; D[h][j] so epilogue is pure float4.
__global__ __launch_bounds__(256, 3) void k_edge1(
    const float* __restrict__ e, const int* __restrict__ mask,
    const float* __restrict__ UeW, const float* __restrict__ Ueb,
    const float* __restrict__ ws, float* __restrict__ out) {
  const int bi = blockIdx.x;
  const int b = bi / N;
  const int tid = threadIdx.x;
  const int w = tid >> 6, lane = tid & 63;
  const int l15 = lane & 15, lg = lane >> 4;
  const int half = w & 1, pair = w >> 1;
  const int hbase = half * 64;

  __shared__ float mrow[N];
  if (tid < N) mrow[tid] = (float)mask[b * N + tid];
  __syncthreads();

  const float mi = (float)mask[bi];
  const float* __restrict__ eg = e + (size_t)bi * NH;

  short8 Wf[4][4];
  #pragma unroll
  for (int ht = 0; ht < 4; ++ht) {
    const float* wr = &UeW[(size_t)(hbase + ht * 16 + l15) * H + lg * 8];
    #pragma unroll
    for (int s = 0; s < 4; ++s) {
      const f32x4 u0 = *(const f32x4*)(wr + s * 32);
      const f32x4 u1 = *(const f32x4*)(wr + s * 32 + 4);
      Wf[ht][s] = pack8(u0, u1);
    }
  }

  // base = Ueb + Vx_i, per lane's 4 consecutive h (h0 = hbase+ht*16+4*lg)
  f32x4 base4[4];
  #pragma unroll
  for (int ht = 0; ht < 4; ++ht) {
    const int h0 = hbase + ht * 16 + 4 * lg;
    const f32x4 ub = *(const f32x4*)&Ueb[h0];
    const f32x4 vx = *(const f32x4*)&ws[WS_VX + (size_t)bi * H + h0];
    base4[ht] = ub + vx;
  }

  auto loadraw = [&](int jt, f32x4* dst) {
    const int jl = min(jt * 16 + l15, N - 1);
    const float* er = eg + (size_t)jl * H + lg * 8;
    #pragma unroll
    for (int s = 0; s < 4; ++s) {
      dst[2 * s]     = *(const f32x4*)(er + s * 32);
      dst[2 * s + 1] = *(const f32x4*)(er + s * 32 + 4);
    }
  };

  f32x4 raw[8];
  loadraw(pair, raw);

  for (int jt = pair; jt < 13; jt += 2) {
    f32x4 nraw[8];
    if (jt + 2 < 13) loadraw(jt + 2, nraw);

    short8 Ef[4];
    #pragma unroll
    for (int s = 0; s < 4; ++s) Ef[s] = pack8(raw[2 * s], raw[2 * s + 1]);

    f32x4 acc[4] = {f32x4(0.f), f32x4(0.f), f32x4(0.f), f32x4(0.f)};
    #pragma unroll
    for (int s = 0; s < 4; ++s) {
      #pragma unroll
      for (int ht = 0; ht < 4; ++ht)   // D[h][j]: col j = l15, row h = ht*16+4*lg+r
        acc[ht] = __builtin_amdgcn_mfma_f32_16x16x32_bf16(Wf[ht][s], Ef[s], acc[ht], 0, 0, 0);
    }

    const int j = jt * 16 + l15;
    if (j < N) {
      const float msk = mi * mrow[j];
      const size_t vrow = (size_t)(b * N + j) * H;
      const size_t erow = (size_t)j * H;
      float* __restrict__ og = out + (size_t)X_SIZE + (size_t)bi * NH + erow;
      #pragma unroll
      for (int ht = 0; ht < 4; ++ht) {
        const int h0 = hbase + ht * 16 + 4 * lg;
        const f32x4 vx4 = *(const f32x4*)&ws[WS_VX + vrow + h0];
        const f32x4 e4  = *(const f32x4*)&eg[erow + h0];    // residual (L1-hot)
        const f32x4 sc4 = *(const f32x4*)&ws[WS_ESC + h0];
        const f32x4 sh4 = *(const f32x4*)&ws[WS_ESH + h0];
        f32x4 o;
        #pragma unroll
        for (int r = 0; r < 4; ++r) {
          const float v = acc[ht][r] + base4[ht][r] + vx4[r];
          const float rr = (msk > 0.f) ? (v * sc4[r] + sh4[r]) : v;
          o[r] = e4[r] + fmaxf(rr, 0.f);
        }
        *(f32x4*)&og[h0] = o;
      }
    }
    #pragma unroll
    for (int k = 0; k < 8; ++k) raw[k] = nraw[k];
  }
}

}  // namespace

extern "C" void kernel_launch(void* const* d_in, const int* in_sizes, int n_in,
                              void* d_out, int out_size, void* d_ws, size_t ws_size,
                              hipStream_t stream) {
  const float* x    = (const float*)d_in[0];
  const float* e    = (const float*)d_in[1];
  const int*   mask = (const int*)d_in[2];
  const float* UeW  = (const float*)d_in[3];
  const float* Ueb  = (const float*)d_in[4];
  const float* VeW  = (const float*)d_in[5];
  const float* Veb  = (const float*)d_in[6];
  const float* UnW  = (const float*)d_in[7];
  const float* Unb  = (const float*)d_in[8];
  const float* VnW  = (const float*)d_in[9];
  const float* Vnb  = (const float*)d_in[10];
  const float* bng  = (const float*)d_in[11];
  const float* bnb  = (const float*)d_in[12];
  const float* beg  = (const float*)d_in[13];
  const float* beb  = (const float*)d_in[14];
  float* ws  = (float*)d_ws;
  float* out = (float*)d_out;

  // zero the slotted stat accumulators (contiguous 4 x 32 x H region)
  hipMemsetAsync(ws + WS_ESUMS, 0, (WS_STAT_END - WS_ESUMS) * sizeof(float), stream);
  k_prep<<<BN, 128, 0, stream>>>(x, mask, VeW, Veb, UnW, Unb, VnW, Vnb, ws);
  k_edge0<<<BN, 256, 0, stream>>>(e, mask, UeW, Ueb, ws);
  k_stats<<<1, 256, 0, stream>>>(mask, beg, beb, bng, bnb, ws);
  k_x2<<<800, 256, 0, stream>>>(x, mask, ws, out);
  k_edge1<<<BN, 256, 0, stream>>>(e, mask, UeW, Ueb, ws, out);
}

// Round 5
// 205.385 us; speedup vs baseline: 1.6793x; 1.6793x over previous
//
#include <hip/hip_runtime.h>
#include <hip/hip_bf16.h>

namespace {

typedef __attribute__((ext_vector_type(8))) short short8;
typedef __attribute__((ext_vector_type(4))) float f32x4;

constexpr int H = 128;
constexpr int N = 200;
constexpr int BN = 1600;          // B*N
constexpr int X_SIZE = BN * H;    // 204800
constexpr int NH = N * H;         // 25600

// ws offsets (floats)
constexpr int WS_VX    = 0;
constexpr int WS_UX    = WS_VX + X_SIZE;
constexpr int WS_VXN   = WS_UX + X_SIZE;
constexpr int WS_XTMP  = WS_VXN + X_SIZE;
constexpr int WS_ESUMS = WS_XTMP + X_SIZE;     // 32 slots x H
constexpr int WS_ESSQS = WS_ESUMS + 32 * H;
constexpr int WS_NSUMS = WS_ESSQS + 32 * H;    // 32 slots x H
constexpr int WS_NSSQS = WS_NSUMS + 32 * H;
constexpr int WS_STAT_END = WS_NSSQS + 32 * H;
constexpr int WS_ESC   = WS_STAT_END;
constexpr int WS_ESH   = WS_ESC + H;
constexpr int WS_NSC   = WS_ESH + H;
constexpr int WS_NSH   = WS_NSC + H;

__device__ __forceinline__ unsigned short f2bf(float f) {
  __hip_bfloat16 h = __float2bfloat16(f);
  return __builtin_bit_cast(unsigned short, h);
}

__device__ __forceinline__ short8 pack8(f32x4 a, f32x4 b) {
  short8 r;
  r[0] = (short)f2bf(a[0]); r[1] = (short)f2bf(a[1]);
  r[2] = (short)f2bf(a[2]); r[3] = (short)f2bf(a[3]);
  r[4] = (short)f2bf(b[0]); r[5] = (short)f2bf(b[1]);
  r[6] = (short)f2bf(b[2]); r[7] = (short)f2bf(b[3]);
  return r;
}

// ---- node linears: Vx, Ux, Vxn (masked) ----
__global__ __launch_bounds__(128) void k_prep(
    const float* __restrict__ x, const int* __restrict__ mask,
    const float* __restrict__ VeW, const float* __restrict__ Veb,
    const float* __restrict__ UnW, const float* __restrict__ Unb,
    const float* __restrict__ VnW, const float* __restrict__ Vnb,
    float* __restrict__ ws) {
  const int bi = blockIdx.x, h = threadIdx.x;
  __shared__ float xr[H];
  xr[h] = x[bi * H + h];
  __syncthreads();
  const float mi = (float)mask[bi];
  float a0 = 0.f, a1 = 0.f, a2 = 0.f;
  #pragma unroll 4
  for (int k = 0; k < H; k += 4) {
    const float x0 = xr[k], x1 = xr[k + 1], x2 = xr[k + 2], x3 = xr[k + 3];
    float4 w;
    w = *(const float4*)&VeW[h * H + k];
    a0 += w.x * x0 + w.y * x1 + w.z * x2 + w.w * x3;
    w = *(const float4*)&UnW[h * H + k];
    a1 += w.x * x0 + w.y * x1 + w.z * x2 + w.w * x3;
    w = *(const float4*)&VnW[h * H + k];
    a2 += w.x * x0 + w.y * x1 + w.z * x2 + w.w * x3;
  }
  ws[WS_VX  + bi * H + h] = mi * (a0 + Veb[h]);
  ws[WS_UX  + bi * H + h] = mi * (a1 + Unb[h]);
  ws[WS_VXN + bi * H + h] = mi * (a2 + Vnb[h]);
}

// ---- pass 0: GEMM + edge stats + sigmoid aggregation + fused x_tmp/node stats ----
// Block = one (b,i). 4 waves; wave w owns h-quarter [32w, 32w+32).
// e-tile (16 x 128) staged via global_load_lds, double-buffered, pre-swizzled source.
// ONE barrier per tile, AFTER compute (prefetch latency hides under MFMA+epilogue).
// Swapped MFMA: D[h][j] -> lane j = l15, h = hbase + ht*16 + 4*lg + r.
__global__ __launch_bounds__(256, 3) void k_edge0(
    const float* __restrict__ e, const int* __restrict__ mask,
    const float* __restrict__ UeW, const float* __restrict__ Ueb,
    float* __restrict__ ws) {
  const int bi = blockIdx.x;
  const int b = bi / N;
  const int tid = threadIdx.x;
  const int w = tid >> 6, lane = tid & 63;
  const int l15 = lane & 15, lg = lane >> 4;
  const int hbase = w * 32;

  __shared__ float etile[2][2048];    // 2 x 8 KB
  __shared__ float mrow[N];
  __shared__ float sS[H], sS2[H], sA[H];

  const float mi = (float)mask[bi];
  const float* __restrict__ eg = e + (size_t)bi * NH;

  auto stage = [&](int buf, int jt) {
    const int j0 = jt * 16;
    #pragma unroll
    for (int ii = 0; ii < 2; ++ii) {
      const int instr = 2 * w + ii;
      const int row = 2 * instr + (lane >> 5);    // 0..15
      const int c16 = lane & 31;                  // 16B chunk within row
      const int gr = min(j0 + row, N - 1);
      const int sc16 = c16 ^ (row & 7);           // pre-swizzled source chunk
      const float* src = eg + (size_t)gr * H + sc16 * 4;
      float* dst = &etile[buf][instr * 256];
      __builtin_amdgcn_global_load_lds(
          (const __attribute__((address_space(1))) void*)src,
          (__attribute__((address_space(3))) void*)dst, 16, 0, 0);
    }
  };

  stage(0, 0);                       // loads in flight during prologue
  if (tid < N) mrow[tid] = (float)mask[b * N + tid];

  // W frags (A-operand): lane holds W[hbase+ht*16+l15][s*32 + lg*8 + 0..7]
  short8 Wf[2][4];
  #pragma unroll
  for (int ht = 0; ht < 2; ++ht) {
    const float* wr = &UeW[(size_t)(hbase + ht * 16 + l15) * H + lg * 8];
    #pragma unroll
    for (int s = 0; s < 4; ++s) {
      const f32x4 u0 = *(const f32x4*)(wr + s * 32);
      const f32x4 u1 = *(const f32x4*)(wr + s * 32 + 4);
      Wf[ht][s] = pack8(u0, u1);
    }
  }
  // base = Ueb + Vx_i at lane's 4 consecutive h
  f32x4 base4[2];
  #pragma unroll
  for (int ht = 0; ht < 2; ++ht) {
    const int h0 = hbase + ht * 16 + 4 * lg;
    const f32x4 ub = *(const f32x4*)&Ueb[h0];
    const f32x4 vx = *(const f32x4*)&ws[WS_VX + (size_t)bi * H + h0];
    base4[ht] = ub + vx;
  }

  float bnS[2][4] = {{0,0,0,0},{0,0,0,0}};
  float bnS2[2][4] = {{0,0,0,0},{0,0,0,0}};
  float ag[2][4] = {{0,0,0,0},{0,0,0,0}};

  __syncthreads();                   // tile 0 staged (startup drain, unavoidable)

  for (int jt = 0; jt < 13; ++jt) {
    const int cur = jt & 1;
    if (jt + 1 < 13) stage(cur ^ 1, jt + 1);   // issue next tile, NOT waited here

    const float* tp = &etile[cur][0];
    short8 Ef[4];                    // B-operand: col j = l15, k = lg*8 + s*32 + 0..7
    #pragma unroll
    for (int s = 0; s < 4; ++s) {
      const int c0 = (lg * 2 + s * 8) ^ (l15 & 7);
      const int c1 = (lg * 2 + s * 8 + 1) ^ (l15 & 7);
      const f32x4 u0 = *(const f32x4*)&tp[l15 * 128 + c0 * 4];
      const f32x4 u1 = *(const f32x4*)&tp[l15 * 128 + c1 * 4];
      Ef[s] = pack8(u0, u1);
    }

    f32x4 acc[2] = {f32x4(0.f), f32x4(0.f)};
    #pragma unroll
    for (int s = 0; s < 4; ++s) {
      #pragma unroll
      for (int ht = 0; ht < 2; ++ht)
        acc[ht] = __builtin_amdgcn_mfma_f32_16x16x32_bf16(Wf[ht][s], Ef[s], acc[ht], 0, 0, 0);
    }

    // epilogue: lane owns one j = jt*16 + l15, h = hbase + ht*16 + 4*lg + r
    const int j = jt * 16 + l15;
    const bool valid = (j < N);
    const int jc = valid ? j : N - 1;
    const float msk = valid ? mi * mrow[jc] : 0.f;
    const float* rv = &ws[WS_VX + (size_t)(b * N + jc) * H];
    const float* rn = &ws[WS_VXN + (size_t)(b * N + jc) * H];
    #pragma unroll
    for (int ht = 0; ht < 2; ++ht) {
      const int h0 = hbase + ht * 16 + 4 * lg;
      const f32x4 vx4 = *(const f32x4*)&rv[h0];
      const f32x4 vn4 = *(const f32x4*)&rn[h0];
      #pragma unroll
      for (int r = 0; r < 4; ++r) {
        const float v = acc[ht][r] + base4[ht][r] + vx4[r];
        bnS[ht][r]  += msk * v;
        bnS2[ht][r] += msk * v * v;
        const float sg = __builtin_amdgcn_rcpf(1.f + __expf(-v));
        ag[ht][r] += msk * sg * vn4[r];
      }
    }
    __syncthreads();   // drain (prefetch landed during compute) + read-safety for etile[cur]
  }

  // reduce stats over j-lanes (l15: xor 1,2,4,8), then one writer per h
  #pragma unroll
  for (int ht = 0; ht < 2; ++ht) {
    #pragma unroll
    for (int r = 0; r < 4; ++r) {
      #pragma unroll
      for (int mm = 1; mm <= 8; mm <<= 1) {
        bnS[ht][r]  += __shfl_xor(bnS[ht][r], mm);
        bnS2[ht][r] += __shfl_xor(bnS2[ht][r], mm);
        ag[ht][r]   += __shfl_xor(ag[ht][r], mm);
      }
    }
  }
  if (l15 == 0) {
    #pragma unroll
    for (int ht = 0; ht < 2; ++ht) {
      #pragma unroll
      for (int r = 0; r < 4; ++r) {
        const int h = hbase + ht * 16 + 4 * lg + r;   // disjoint across writers
        sS[h] = bnS[ht][r]; sS2[h] = bnS2[ht][r]; sA[h] = ag[ht][r];
      }
    }
  }
  __syncthreads();
  if (tid < H) {
    const int slot = (bi & 31) * H + tid;
    atomicAdd(&ws[WS_ESUMS + slot], sS[tid]);
    atomicAdd(&ws[WS_ESSQS + slot], sS2[tid]);
    // fused x_tmp = Ux + agg, plus node BN partials
    const float v = ws[WS_UX + (size_t)bi * H + tid] + sA[tid];
    ws[WS_XTMP + (size_t)bi * H + tid] = v;
    atomicAdd(&ws[WS_NSUMS + slot], mi * v);
    atomicAdd(&ws[WS_NSSQS + slot], mi * v * v);
  }
}

// ---- counts + finalize BN scale/shift for edge and node ----
__global__ void k_stats(const int* __restrict__ mask,
                        const float* __restrict__ beg, const float* __restrict__ beb,
                        const float* __restrict__ bng, const float* __restrict__ bnb,
                        float* __restrict__ ws) {
  __shared__ float sb[8];
  const int t = threadIdx.x;          // 256 threads
  const int b = t >> 5, li = t & 31;
  float s = 0.f;
  for (int i = li; i < N; i += 32) s += (float)mask[b * N + i];
  #pragma unroll
  for (int o = 16; o >= 1; o >>= 1) s += __shfl_down(s, o, 32);
  if (li == 0) sb[b] = s;
  __syncthreads();
  if (t < H) {
    float cn = 0.f, ce = 0.f;
    #pragma unroll
    for (int bb = 0; bb < 8; ++bb) { cn += sb[bb]; ce += sb[bb] * sb[bb]; }
    ce = fmaxf(ce, 1.f); cn = fmaxf(cn, 1.f);
    float es = 0.f, es2 = 0.f, ns = 0.f, ns2 = 0.f;
    #pragma unroll 4
    for (int k = 0; k < 32; ++k) {
      es  += ws[WS_ESUMS + k * H + t];
      es2 += ws[WS_ESSQS + k * H + t];
      ns  += ws[WS_NSUMS + k * H + t];
      ns2 += ws[WS_NSSQS + k * H + t];
    }
    const float me = es / ce;
    const float ve = fmaxf(es2 / ce - me * me, 0.f);
    const float se = rsqrtf(ve + 1e-5f) * beg[t];
    ws[WS_ESC + t] = se;
    ws[WS_ESH + t] = beb[t] - me * se;
    const float mn = ns / cn;
    const float vn = fmaxf(ns2 / cn - mn * mn, 0.f);
    const float sn = rsqrtf(vn + 1e-5f) * bng[t];
    ws[WS_NSC + t] = sn;
    ws[WS_NSH + t] = bnb[t] - mn * sn;
  }
}

// ---- x_new = x + relu(masked BN(x_tmp)) ----
__global__ void k_x2(const float* __restrict__ x, const int* __restrict__ mask,
                     const float* __restrict__ ws, float* __restrict__ out) {
  const int idx = blockIdx.x * 256 + threadIdx.x;
  if (idx >= X_SIZE) return;
  const int h = idx & 127, bi = idx >> 7;
  const float v = ws[WS_XTMP + idx];
  const float r = (mask[bi] != 0) ? (v * ws[WS_NSC + h] + ws[WS_NSH + h]) : v;
  out[idx] = x[idx] + fmaxf(r, 0.f);
}

// ---- pass 1: recompute e_tmp, normalize + residual + write ----
// Same pipeline skeleton as pass 0; residual e read from the staged LDS tile.
__global__ __launch_bounds__(256, 3) void k_edge1(
    const float* __restrict__ e, const int* __restrict__ mask,
    const float* __restrict__ UeW, const float* __restrict__ Ueb,
    const float* __restrict__ ws, float* __restrict__ out) {
  const int bi = blockIdx.x;
  const int b = bi / N;
  const int tid = threadIdx.x;
  const int w = tid >> 6, lane = tid & 63;
  const int l15 = lane & 15, lg = lane >> 4;
  const int hbase = w * 32;

  __shared__ float etile[2][2048];
  __shared__ float mrow[N];

  const float mi = (float)mask[bi];
  const float* __restrict__ eg = e + (size_t)bi * NH;

  auto stage = [&](int buf, int jt) {
    const int j0 = jt * 16;
    #pragma unroll
    for (int ii = 0; ii < 2; ++ii) {
      const int instr = 2 * w + ii;
      const int row = 2 * instr + (lane >> 5);
      const int c16 = lane & 31;
      const int gr = min(j0 + row, N - 1);
      const int sc16 = c16 ^ (row & 7);
      const float* src = eg + (size_t)gr * H + sc16 * 4;
      float* dst = &etile[buf][instr * 256];
      __builtin_amdgcn_global_load_lds(
          (const __attribute__((address_space(1))) void*)src,
          (__attribute__((address_space(3))) void*)dst, 16, 0, 0);
    }
  };

  stage(0, 0);
  if (tid < N) mrow[tid] = (float)mask[b * N + tid];

  short8 Wf[2][4];
  #pragma unroll
  for (int ht = 0; ht < 2; ++ht) {
    const float* wr = &UeW[(size_t)(hbase + ht * 16 + l15) * H + lg * 8];
    #pragma unroll
    for (int s = 0; s < 4; ++s) {
      const f32x4 u0 = *(const f32x4*)(wr + s * 32);
      const f32x4 u1 = *(const f32x4*)(wr + s * 32 + 4);
      Wf[ht][s] = pack8(u0, u1);
    }
  }
  f32x4 base4[2], sc4[2], sh4[2];
  #pragma unroll
  for (int ht = 0; ht < 2; ++ht) {
    const int h0 = hbase + ht * 16 + 4 * lg;
    const f32x4 ub = *(const f32x4*)&Ueb[h0];
    const f32x4 vx = *(const f32x4*)&ws[WS_VX + (size_t)bi * H + h0];
    base4[ht] = ub + vx;
    sc4[ht] = *(const f32x4*)&ws[WS_ESC + h0];
    sh4[ht] = *(const f32x4*)&ws[WS_ESH + h0];
  }

  __syncthreads();                   // tile 0 staged

  for (int jt = 0; jt < 13; ++jt) {
    const int cur = jt & 1;
    if (jt + 1 < 13) stage(cur ^ 1, jt + 1);

    const float* tp = &etile[cur][0];
    short8 Ef[4];
    #pragma unroll
    for (int s = 0; s < 4; ++s) {
      const int c0 = (lg * 2 + s * 8) ^ (l15 & 7);
      const int c1 = (lg * 2 + s * 8 + 1) ^ (l15 & 7);
      const f32x4 u0 = *(const f32x4*)&tp[l15 * 128 + c0 * 4];
      const f32x4 u1 = *(const f32x4*)&tp[l15 * 128 + c1 * 4];
      Ef[s] = pack8(u0, u1);
    }

    f32x4 acc[2] = {f32x4(0.f), f32x4(0.f)};
    #pragma unroll
    for (int s = 0; s < 4; ++s) {
      #pragma unroll
      for (int ht = 0; ht < 2; ++ht)
        acc[ht] = __builtin_amdgcn_mfma_f32_16x16x32_bf16(Wf[ht][s], Ef[s], acc[ht], 0, 0, 0);
    }

    const int j = jt * 16 + l15;
    if (j < N) {
      const float msk = mi * mrow[j];
      const float* rv = &ws[WS_VX + (size_t)(b * N + j) * H];
      float* __restrict__ og = out + (size_t)X_SIZE + (size_t)bi * NH + (size_t)j * H;
      #pragma unroll
      for (int ht = 0; ht < 2; ++ht) {
        const int h0 = hbase + ht * 16 + 4 * lg;
        const f32x4 vx4 = *(const f32x4*)&rv[h0];
        // residual from the staged (swizzled) LDS tile
        const int ch = (h0 >> 2) ^ (l15 & 7);
        const f32x4 e4 = *(const f32x4*)&tp[l15 * 128 + ch * 4];
        f32x4 o;
        #pragma unroll
        for (int r = 0; r < 4; ++r) {
          const float v = acc[ht][r] + base4[ht][r] + vx4[r];
          const float rr = (msk > 0.f) ? (v * sc4[ht][r] + sh4[ht][r]) : v;
          o[r] = e4[r] + fmaxf(rr, 0.f);
        }
        *(f32x4*)&og[h0] = o;
      }
    }
    __syncthreads();
  }
}

}  // namespace

extern "C" void kernel_launch(void* const* d_in, const int* in_sizes, int n_in,
                              void* d_out, int out_size, void* d_ws, size_t ws_size,
                              hipStream_t stream) {
  const float* x    = (const float*)d_in[0];
  const float* e    = (const float*)d_in[1];
  const int*   mask = (const int*)d_in[2];
  const float* UeW  = (const float*)d_in[3];
  const float* Ueb  = (const float*)d_in[4];
  const float* VeW  = (const float*)d_in[5];
  const float* Veb  = (const float*)d_in[6];
  const float* UnW  = (const float*)d_in[7];
  const float* Unb  = (const float*)d_in[8];
  const float* VnW  = (const float*)d_in[9];
  const float* Vnb  = (const float*)d_in[10];
  const float* bng  = (const float*)d_in[11];
  const float* bnb  = (const float*)d_in[12];
  const float* beg  = (const float*)d_in[13];
  const float* beb  = (const float*)d_in[14];
  float* ws  = (float*)d_ws;
  float* out = (float*)d_out;

  // zero the slotted stat accumulators (contiguous 4 x 32 x H region)
  hipMemsetAsync(ws + WS_ESUMS, 0, (WS_STAT_END - WS_ESUMS) * sizeof(float), stream);
  k_prep<<<BN, 128, 0, stream>>>(x, mask, VeW, Veb, UnW, Unb, VnW, Vnb, ws);
  k_edge0<<<BN, 256, 0, stream>>>(e, mask, UeW, Ueb, ws);
  k_stats<<<1, 256, 0, stream>>>(mask, beg, beb, bng, bnb, ws);
  k_x2<<<800, 256, 0, stream>>>(x, mask, ws, out);
  k_edge1<<<BN, 256, 0, stream>>>(e, mask, UeW, Ueb, ws, out);
}

// Round 6
// 194.720 us; speedup vs baseline: 1.7713x; 1.0548x over previous
//
#include <hip/hip_runtime.h>
#include <hip/hip_bf16.h>

namespace {

typedef __attribute__((ext_vector_type(8))) short short8;
typedef __attribute__((ext_vector_type(4))) float f32x4;

constexpr int H = 128;
constexpr int N = 200;
constexpr int BN = 1600;          // B*N
constexpr int X_SIZE = BN * H;    // 204800
constexpr int NH = N * H;         // 25600

// ws offsets (floats)
constexpr int WS_VX    = 0;
constexpr int WS_UX    = WS_VX + X_SIZE;
constexpr int WS_VXN   = WS_UX + X_SIZE;
constexpr int WS_XTMP  = WS_VXN + X_SIZE;
constexpr int WS_ESUMS = WS_XTMP + X_SIZE;     // 32 slots x H
constexpr int WS_ESSQS = WS_ESUMS + 32 * H;
constexpr int WS_NSUMS = WS_ESSQS + 32 * H;    // 32 slots x H
constexpr int WS_NSSQS = WS_NSUMS + 32 * H;
constexpr int WS_STAT_END = WS_NSSQS + 32 * H;
constexpr int WS_ESC   = WS_STAT_END;
constexpr int WS_ESH   = WS_ESC + H;
constexpr int WS_NSC   = WS_ESH + H;
constexpr int WS_NSH   = WS_NSC + H;

__device__ __forceinline__ unsigned short f2bf(float f) {
  __hip_bfloat16 h = __float2bfloat16(f);
  return __builtin_bit_cast(unsigned short, h);
}

__device__ __forceinline__ short8 pack8(f32x4 a, f32x4 b) {
  short8 r;
  r[0] = (short)f2bf(a[0]); r[1] = (short)f2bf(a[1]);
  r[2] = (short)f2bf(a[2]); r[3] = (short)f2bf(a[3]);
  r[4] = (short)f2bf(b[0]); r[5] = (short)f2bf(b[1]);
  r[6] = (short)f2bf(b[2]); r[7] = (short)f2bf(b[3]);
  return r;
}

// ---- node linears: Vx, Ux, Vxn (masked) ----
__global__ __launch_bounds__(128) void k_prep(
    const float* __restrict__ x, const int* __restrict__ mask,
    const float* __restrict__ VeW, const float* __restrict__ Veb,
    const float* __restrict__ UnW, const float* __restrict__ Unb,
    const float* __restrict__ VnW, const float* __restrict__ Vnb,
    float* __restrict__ ws) {
  const int bi = blockIdx.x, h = threadIdx.x;
  __shared__ float xr[H];
  xr[h] = x[bi * H + h];
  __syncthreads();
  const float mi = (float)mask[bi];
  float a0 = 0.f, a1 = 0.f, a2 = 0.f;
  #pragma unroll 4
  for (int k = 0; k < H; k += 4) {
    const float x0 = xr[k], x1 = xr[k + 1], x2 = xr[k + 2], x3 = xr[k + 3];
    float4 w;
    w = *(const float4*)&VeW[h * H + k];
    a0 += w.x * x0 + w.y * x1 + w.z * x2 + w.w * x3;
    w = *(const float4*)&UnW[h * H + k];
    a1 += w.x * x0 + w.y * x1 + w.z * x2 + w.w * x3;
    w = *(const float4*)&VnW[h * H + k];
    a2 += w.x * x0 + w.y * x1 + w.z * x2 + w.w * x3;
  }
  ws[WS_VX  + bi * H + h] = mi * (a0 + Veb[h]);
  ws[WS_UX  + bi * H + h] = mi * (a1 + Unb[h]);
  ws[WS_VXN + bi * H + h] = mi * (a2 + Vnb[h]);
}

// ---- pass 0: GEMM + edge stats + sigmoid aggregation + fused x_tmp/node stats ----
// Block = one (b,i). 4 waves; wave w owns h-quarter [32w, 32w+32).
// e, Vx, Vxn tiles (16 x 128 each) ALL staged via global_load_lds (pre-swizzled
// source), double-buffered. The loop body consumes ONLY LDS + registers, so the
// end-of-iter __syncthreads drain happens after the prefetch had the whole
// compute phase to land (no mid-iter vmcnt drain from epilogue global loads).
// Swapped MFMA: D[h][j] -> lane owns j = l15, h = hbase + ht*16 + 4*lg + r.
__global__ __launch_bounds__(256, 3) void k_edge0(
    const float* __restrict__ e, const int* __restrict__ mask,
    const float* __restrict__ UeW, const float* __restrict__ Ueb,
    float* __restrict__ ws) {
  const int bi = blockIdx.x;
  const int b = bi / N;
  const int tid = threadIdx.x;
  const int w = tid >> 6, lane = tid & 63;
  const int l15 = lane & 15, lg = lane >> 4;
  const int hbase = w * 32;

  __shared__ float lds[2][3 * 2048];   // [buf][e | vx | vxn], 48 KB
  __shared__ float mrow[N];
  __shared__ float sS[H], sS2[H], sA[H];

  const float mi = (float)mask[bi];
  const float* __restrict__ eg  = e + (size_t)bi * NH;
  const float* __restrict__ vxg = ws + WS_VX  + (size_t)b * NH;
  const float* __restrict__ vng = ws + WS_VXN + (size_t)b * NH;

  // 6 global_load_lds per wave per tile (2 instr x 3 arrays), source pre-swizzled
  auto stage = [&](int buf, int jt) {
    const int j0 = jt * 16;
    #pragma unroll
    for (int ii = 0; ii < 2; ++ii) {
      const int instr = 2 * w + ii;               // 0..7
      const int row = 2 * instr + (lane >> 5);    // 0..15
      const int gr = min(j0 + row, N - 1);
      const int sc16 = (lane & 31) ^ (row & 7);   // swizzled 16B chunk
      const size_t so = (size_t)gr * H + sc16 * 4;
      float* dst = &lds[buf][instr * 256];
      __builtin_amdgcn_global_load_lds(
          (const __attribute__((address_space(1))) void*)(eg + so),
          (__attribute__((address_space(3))) void*)dst, 16, 0, 0);
      __builtin_amdgcn_global_load_lds(
          (const __attribute__((address_space(1))) void*)(vxg + so),
          (__attribute__((address_space(3))) void*)(dst + 2048), 16, 0, 0);
      __builtin_amdgcn_global_load_lds(
          (const __attribute__((address_space(1))) void*)(vng + so),
          (__attribute__((address_space(3))) void*)(dst + 4096), 16, 0, 0);
    }
  };

  stage(0, 0);                       // in flight during prologue
  if (tid < N) mrow[tid] = (float)mask[b * N + tid];

  // W frags (A-operand): lane holds W[hbase+ht*16+l15][s*32 + lg*8 + 0..7]
  short8 Wf[2][4];
  #pragma unroll
  for (int ht = 0; ht < 2; ++ht) {
    const float* wr = &UeW[(size_t)(hbase + ht * 16 + l15) * H + lg * 8];
    #pragma unroll
    for (int s = 0; s < 4; ++s) {
      const f32x4 u0 = *(const f32x4*)(wr + s * 32);
      const f32x4 u1 = *(const f32x4*)(wr + s * 32 + 4);
      Wf[ht][s] = pack8(u0, u1);
    }
  }
  // base = Ueb + Vx_i at lane's 4 consecutive h
  f32x4 base4[2];
  #pragma unroll
  for (int ht = 0; ht < 2; ++ht) {
    const int h0 = hbase + ht * 16 + 4 * lg;
    const f32x4 ub = *(const f32x4*)&Ueb[h0];
    const f32x4 vx = *(const f32x4*)&ws[WS_VX + (size_t)bi * H + h0];
    base4[ht] = ub + vx;
  }

  float bnS[2][4] = {{0,0,0,0},{0,0,0,0}};
  float bnS2[2][4] = {{0,0,0,0},{0,0,0,0}};
  float ag[2][4] = {{0,0,0,0},{0,0,0,0}};

  __syncthreads();                   // tile 0 + mrow ready (startup drain)

  for (int jt = 0; jt < 13; ++jt) {
    const int cur = jt & 1;
    if (jt + 1 < 13) stage(cur ^ 1, jt + 1);   // overlaps whole compute phase

    const float* tp = &lds[cur][0];
    short8 Ef[4];                    // B-operand: col j = l15, k = lg*8 + s*32 + 0..7
    #pragma unroll
    for (int s = 0; s < 4; ++s) {
      const int c0 = (lg * 2 + s * 8) ^ (l15 & 7);
      const int c1 = (lg * 2 + s * 8 + 1) ^ (l15 & 7);
      const f32x4 u0 = *(const f32x4*)&tp[l15 * 128 + c0 * 4];
      const f32x4 u1 = *(const f32x4*)&tp[l15 * 128 + c1 * 4];
      Ef[s] = pack8(u0, u1);
    }

    f32x4 acc[2] = {f32x4(0.f), f32x4(0.f)};
    #pragma unroll
    for (int s = 0; s < 4; ++s) {
      #pragma unroll
      for (int ht = 0; ht < 2; ++ht)
        acc[ht] = __builtin_amdgcn_mfma_f32_16x16x32_bf16(Wf[ht][s], Ef[s], acc[ht], 0, 0, 0);
    }

    // epilogue: LDS + registers only (NO global loads -> no vmcnt drain mid-iter)
    const int j = jt * 16 + l15;
    const bool valid = (j < N);
    const float msk = valid ? mi * mrow[valid ? j : 0] : 0.f;
    #pragma unroll
    for (int ht = 0; ht < 2; ++ht) {
      const int h0 = hbase + ht * 16 + 4 * lg;
      const int ch = (h0 >> 2) ^ (l15 & 7);
      const f32x4 vx4 = *(const f32x4*)&tp[2048 + l15 * 128 + ch * 4];
      const f32x4 vn4 = *(const f32x4*)&tp[4096 + l15 * 128 + ch * 4];
      #pragma unroll
      for (int r = 0; r < 4; ++r) {
        const float v = acc[ht][r] + base4[ht][r] + vx4[r];
        bnS[ht][r]  += msk * v;
        bnS2[ht][r] += msk * v * v;
        const float sg = __builtin_amdgcn_rcpf(1.f + __expf(-v));
        ag[ht][r] += msk * sg * vn4[r];
      }
    }
    __syncthreads();   // drain: prefetch landed during compute; read-safety for lds[cur]
  }

  // reduce stats over j-lanes (l15: xor 1,2,4,8), then one writer per h
  #pragma unroll
  for (int ht = 0; ht < 2; ++ht) {
    #pragma unroll
    for (int r = 0; r < 4; ++r) {
      #pragma unroll
      for (int mm = 1; mm <= 8; mm <<= 1) {
        bnS[ht][r]  += __shfl_xor(bnS[ht][r], mm);
        bnS2[ht][r] += __shfl_xor(bnS2[ht][r], mm);
        ag[ht][r]   += __shfl_xor(ag[ht][r], mm);
      }
    }
  }
  if (l15 == 0) {
    #pragma unroll
    for (int ht = 0; ht < 2; ++ht) {
      #pragma unroll
      for (int r = 0; r < 4; ++r) {
        const int h = hbase + ht * 16 + 4 * lg + r;   // disjoint across writers
        sS[h] = bnS[ht][r]; sS2[h] = bnS2[ht][r]; sA[h] = ag[ht][r];
      }
    }
  }
  __syncthreads();
  if (tid < H) {
    const int slot = (bi & 31) * H + tid;
    atomicAdd(&ws[WS_ESUMS + slot], sS[tid]);
    atomicAdd(&ws[WS_ESSQS + slot], sS2[tid]);
    // fused x_tmp = Ux + agg, plus node BN partials
    const float v = ws[WS_UX + (size_t)bi * H + tid] + sA[tid];
    ws[WS_XTMP + (size_t)bi * H + tid] = v;
    atomicAdd(&ws[WS_NSUMS + slot], mi * v);
    atomicAdd(&ws[WS_NSSQS + slot], mi * v * v);
  }
}

// ---- counts + finalize BN scale/shift for edge and node ----
__global__ void k_stats(const int* __restrict__ mask,
                        const float* __restrict__ beg, const float* __restrict__ beb,
                        const float* __restrict__ bng, const float* __restrict__ bnb,
                        float* __restrict__ ws) {
  __shared__ float sb[8];
  const int t = threadIdx.x;          // 256 threads
  const int b = t >> 5, li = t & 31;
  float s = 0.f;
  for (int i = li; i < N; i += 32) s += (float)mask[b * N + i];
  #pragma unroll
  for (int o = 16; o >= 1; o >>= 1) s += __shfl_down(s, o, 32);
  if (li == 0) sb[b] = s;
  __syncthreads();
  if (t < H) {
    float cn = 0.f, ce = 0.f;
    #pragma unroll
    for (int bb = 0; bb < 8; ++bb) { cn += sb[bb]; ce += sb[bb] * sb[bb]; }
    ce = fmaxf(ce, 1.f); cn = fmaxf(cn, 1.f);
    float es = 0.f, es2 = 0.f, ns = 0.f, ns2 = 0.f;
    #pragma unroll 4
    for (int k = 0; k < 32; ++k) {
      es  += ws[WS_ESUMS + k * H + t];
      es2 += ws[WS_ESSQS + k * H + t];
      ns  += ws[WS_NSUMS + k * H + t];
      ns2 += ws[WS_NSSQS + k * H + t];
    }
    const float me = es / ce;
    const float ve = fmaxf(es2 / ce - me * me, 0.f);
    const float se = rsqrtf(ve + 1e-5f) * beg[t];
    ws[WS_ESC + t] = se;
    ws[WS_ESH + t] = beb[t] - me * se;
    const float mn = ns / cn;
    const float vn = fmaxf(ns2 / cn - mn * mn, 0.f);
    const float sn = rsqrtf(vn + 1e-5f) * bng[t];
    ws[WS_NSC + t] = sn;
    ws[WS_NSH + t] = bnb[t] - mn * sn;
  }
}

// ---- x_new = x + relu(masked BN(x_tmp)) ----
__global__ void k_x2(const float* __restrict__ x, const int* __restrict__ mask,
                     const float* __restrict__ ws, float* __restrict__ out) {
  const int idx = blockIdx.x * 256 + threadIdx.x;
  if (idx >= X_SIZE) return;
  const int h = idx & 127, bi = idx >> 7;
  const float v = ws[WS_XTMP + idx];
  const float r = (mask[bi] != 0) ? (v * ws[WS_NSC + h] + ws[WS_NSH + h]) : v;
  out[idx] = x[idx] + fmaxf(r, 0.f);
}

// ---- pass 1: recompute e_tmp, normalize + residual + write ----
// Same pipeline; stages e + Vx only. Epilogue: regs/LDS + stores (no global loads).
__global__ __launch_bounds__(256, 3) void k_edge1(
    const float* __restrict__ e, const int* __restrict__ mask,
    const float* __restrict__ UeW, const float* __restrict__ Ueb,
    const float* __restrict__ ws, float* __restrict__ out) {
  const int bi = blockIdx.x;
  const int b = bi / N;
  const int tid = threadIdx.x;
  const int w = tid >> 6, lane = tid & 63;
  const int l15 = lane & 15, lg = lane >> 4;
  const int hbase = w * 32;

  __shared__ float lds[2][2 * 2048];   // [buf][e | vx], 32 KB
  __shared__ float mrow[N];

  const float mi = (float)mask[bi];
  const float* __restrict__ eg  = e + (size_t)bi * NH;
  const float* __restrict__ vxg = ws + WS_VX + (size_t)b * NH;

  auto stage = [&](int buf, int jt) {
    const int j0 = jt * 16;
    #pragma unroll
    for (int ii = 0; ii < 2; ++ii) {
      const int instr = 2 * w + ii;
      const int row = 2 * instr + (lane >> 5);
      const int gr = min(j0 + row, N - 1);
      const int sc16 = (lane & 31) ^ (row & 7);
      const size_t so = (size_t)gr * H + sc16 * 4;
      float* dst = &lds[buf][instr * 256];
      __builtin_amdgcn_global_load_lds(
          (const __attribute__((address_space(1))) void*)(eg + so),
          (__attribute__((address_space(3))) void*)dst, 16, 0, 0);
      __builtin_amdgcn_global_load_lds(
          (const __attribute__((address_space(1))) void*)(vxg + so),
          (__attribute__((address_space(3))) void*)(dst + 2048), 16, 0, 0);
    }
  };

  stage(0, 0);
  if (tid < N) mrow[tid] = (float)mask[b * N + tid];

  short8 Wf[2][4];
  #pragma unroll
  for (int ht = 0; ht < 2; ++ht) {
    const float* wr = &UeW[(size_t)(hbase + ht * 16 + l15) * H + lg * 8];
    #pragma unroll
    for (int s = 0; s < 4; ++s) {
      const f32x4 u0 = *(const f32x4*)(wr + s * 32);
      const f32x4 u1 = *(const f32x4*)(wr + s * 32 + 4);
      Wf[ht][s] = pack8(u0, u1);
    }
  }
  f32x4 base4[2], sc4[2], sh4[2];
  #pragma unroll
  for (int ht = 0; ht < 2; ++ht) {
    const int h0 = hbase + ht * 16 + 4 * lg;
    const f32x4 ub = *(const f32x4*)&Ueb[h0];
    const f32x4 vx = *(const f32x4*)&ws[WS_VX + (size_t)bi * H + h0];
    base4[ht] = ub + vx;
    sc4[ht] = *(const f32x4*)&ws[WS_ESC + h0];
    sh4[ht] = *(const f32x4*)&ws[WS_ESH + h0];
  }

  __syncthreads();                   // tile 0 staged

  for (int jt = 0; jt < 13; ++jt) {
    const int cur = jt & 1;
    if (jt + 1 < 13) stage(cur ^ 1, jt + 1);

    const float* tp = &lds[cur][0];
    short8 Ef[4];
    #pragma unroll
    for (int s = 0; s < 4; ++s) {
      const int c0 = (lg * 2 + s * 8) ^ (l15 & 7);
      const int c1 = (lg * 2 + s * 8 + 1) ^ (l15 & 7);
      const f32x4 u0 = *(const f32x4*)&tp[l15 * 128 + c0 * 4];
      const f32x4 u1 = *(const f32x4*)&tp[l15 * 128 + c1 * 4];
      Ef[s] = pack8(u0, u1);
    }

    f32x4 acc[2] = {f32x4(0.f), f32x4(0.f)};
    #pragma unroll
    for (int s = 0; s < 4; ++s) {
      #pragma unroll
      for (int ht = 0; ht < 2; ++ht)
        acc[ht] = __builtin_amdgcn_mfma_f32_16x16x32_bf16(Wf[ht][s], Ef[s], acc[ht], 0, 0, 0);
    }

    const int j = jt * 16 + l15;
    if (j < N) {
      const float msk = mi * mrow[j];
      float* __restrict__ og = out + (size_t)X_SIZE + (size_t)bi * NH + (size_t)j * H;
      #pragma unroll
      for (int ht = 0; ht < 2; ++ht) {
        const int h0 = hbase + ht * 16 + 4 * lg;
        const int ch = (h0 >> 2) ^ (l15 & 7);
        const f32x4 vx4 = *(const f32x4*)&tp[2048 + l15 * 128 + ch * 4];
        const f32x4 e4  = *(const f32x4*)&tp[l15 * 128 + ch * 4];   // residual
        f32x4 o;
        #pragma unroll
        for (int r = 0; r < 4; ++r) {
          const float v = acc[ht][r] + base4[ht][r] + vx4[r];
          const float rr = (msk > 0.f) ? (v * sc4[ht][r] + sh4[ht][r]) : v;
          o[r] = e4[r] + fmaxf(rr, 0.f);
        }
        *(f32x4*)&og[h0] = o;
      }
    }
    __syncthreads();
  }
}

}  // namespace

extern "C" void kernel_launch(void* const* d_in, const int* in_sizes, int n_in,
                              void* d_out, int out_size, void* d_ws, size_t ws_size,
                              hipStream_t stream) {
  const float* x    = (const float*)d_in[0];
  const float* e    = (const float*)d_in[1];
  const int*   mask = (const int*)d_in[2];
  const float* UeW  = (const float*)d_in[3];
  const float* Ueb  = (const float*)d_in[4];
  const float* VeW  = (const float*)d_in[5];
  const float* Veb  = (const float*)d_in[6];
  const float* UnW  = (const float*)d_in[7];
  const float* Unb  = (const float*)d_in[8];
  const float* VnW  = (const float*)d_in[9];
  const float* Vnb  = (const float*)d_in[10];
  const float* bng  = (const float*)d_in[11];
  const float* bnb  = (const float*)d_in[12];
  const float* beg  = (const float*)d_in[13];
  const float* beb  = (const float*)d_in[14];
  float* ws  = (float*)d_ws;
  float* out = (float*)d_out;

  // zero the slotted stat accumulators (contiguous 4 x 32 x H region)
  hipMemsetAsync(ws + WS_ESUMS, 0, (WS_STAT_END - WS_ESUMS) * sizeof(float), stream);
  k_prep<<<BN, 128, 0, stream>>>(x, mask, VeW, Veb, UnW, Unb, VnW, Vnb, ws);
  k_edge0<<<BN, 256, 0, stream>>>(e, mask, UeW, Ueb, ws);
  k_stats<<<1, 256, 0, stream>>>(mask, beg, beb, bng, bnb, ws);
  k_x2<<<800, 256, 0, stream>>>(x, mask, ws, out);
  k_edge1<<<BN, 256, 0, stream>>>(e, mask, UeW, Ueb, ws, out);
}

// Round 8
// 189.809 us; speedup vs baseline: 1.8171x; 1.0259x over previous
//
#include <hip/hip_runtime.h>
#include <hip/hip_bf16.h>

namespace {

typedef __attribute__((ext_vector_type(8))) short short8;
typedef __attribute__((ext_vector_type(4))) float f32x4;

constexpr int H = 128;
constexpr int N = 200;
constexpr int BN = 1600;          // B*N
constexpr int X_SIZE = BN * H;    // 204800
constexpr int NH = N * H;         // 25600

// ws offsets (floats)
constexpr int WS_VX    = 0;
constexpr int WS_UX    = WS_VX + X_SIZE;
constexpr int WS_VXN   = WS_UX + X_SIZE;
constexpr int WS_XTMP  = WS_VXN + X_SIZE;
constexpr int WS_ESUMS = WS_XTMP + X_SIZE;     // 32 slots x H
constexpr int WS_ESSQS = WS_ESUMS + 32 * H;
constexpr int WS_NSUMS = WS_ESSQS + 32 * H;    // 32 slots x H
constexpr int WS_NSSQS = WS_NSUMS + 32 * H;
constexpr int WS_STAT_END = WS_NSSQS + 32 * H;
constexpr int WS_ESC   = WS_STAT_END;
constexpr int WS_ESH   = WS_ESC + H;
constexpr int WS_NSC   = WS_ESH + H;
constexpr int WS_NSH   = WS_NSC + H;

__device__ __forceinline__ unsigned short f2bf(float f) {
  __hip_bfloat16 h = __float2bfloat16(f);
  return __builtin_bit_cast(unsigned short, h);
}

__device__ __forceinline__ short8 pack8(f32x4 a, f32x4 b) {
  short8 r;
  r[0] = (short)f2bf(a[0]); r[1] = (short)f2bf(a[1]);
  r[2] = (short)f2bf(a[2]); r[3] = (short)f2bf(a[3]);
  r[4] = (short)f2bf(b[0]); r[5] = (short)f2bf(b[1]);
  r[6] = (short)f2bf(b[2]); r[7] = (short)f2bf(b[3]);
  return r;
}

// ---- node linears: Vx, Ux, Vxn (masked) ----
__global__ __launch_bounds__(128) void k_prep(
    const float* __restrict__ x, const int* __restrict__ mask,
    const float* __restrict__ VeW, const float* __restrict__ Veb,
    const float* __restrict__ UnW, const float* __restrict__ Unb,
    const float* __restrict__ VnW, const float* __restrict__ Vnb,
    float* __restrict__ ws) {
  const int bi = blockIdx.x, h = threadIdx.x;
  __shared__ float xr[H];
  xr[h] = x[bi * H + h];
  __syncthreads();
  const float mi = (float)mask[bi];
  float a0 = 0.f, a1 = 0.f, a2 = 0.f;
  #pragma unroll 4
  for (int k = 0; k < H; k += 4) {
    const float x0 = xr[k], x1 = xr[k + 1], x2 = xr[k + 2], x3 = xr[k + 3];
    float4 w;
    w = *(const float4*)&VeW[h * H + k];
    a0 += w.x * x0 + w.y * x1 + w.z * x2 + w.w * x3;
    w = *(const float4*)&UnW[h * H + k];
    a1 += w.x * x0 + w.y * x1 + w.z * x2 + w.w * x3;
    w = *(const float4*)&VnW[h * H + k];
    a2 += w.x * x0 + w.y * x1 + w.z * x2 + w.w * x3;
  }
  ws[WS_VX  + bi * H + h] = mi * (a0 + Veb[h]);
  ws[WS_UX  + bi * H + h] = mi * (a1 + Unb[h]);
  ws[WS_VXN + bi * H + h] = mi * (a2 + Vnb[h]);
}

// ---- pass 0: GEMM + edge stats + sigmoid aggregation + fused x_tmp/node stats ----
// Counted-vmcnt pipeline (T3+T4): 6 loads/stage, prologue stages 2 tiles (12
// outstanding). Top-of-iter s_waitcnt vmcnt(6) == "stage(jt) landed, stage(jt+1)
// stays in flight". Raw s_barrier (no implicit drain). Second barrier after
// lgkmcnt(0) gives read-safety before stage(jt+2) overwrites the buffer.
// No vmcnt(0) in the main loop. (Validated correct in round 7: output 0 passed.)
__global__ __launch_bounds__(256, 3) void k_edge0(
    const float* __restrict__ e, const int* __restrict__ mask,
    const float* __restrict__ UeW, const float* __restrict__ Ueb,
    float* __restrict__ ws) {
  const int bi = blockIdx.x;
  const int b = bi / N;
  const int tid = threadIdx.x;
  const int w = tid >> 6, lane = tid & 63;
  const int l15 = lane & 15, lg = lane >> 4;
  const int hbase = w * 32;

  __shared__ float lds[2][3 * 2048];   // [buf][e | vx | vxn], 48 KB
  __shared__ float mrow[N];
  __shared__ float sS[H], sS2[H], sA[H];

  const float mi = (float)mask[bi];
  const float* __restrict__ eg  = e + (size_t)bi * NH;
  const float* __restrict__ vxg = ws + WS_VX  + (size_t)b * NH;
  const float* __restrict__ vng = ws + WS_VXN + (size_t)b * NH;

  // 6 global_load_lds per wave per tile (2 instr x 3 arrays), source pre-swizzled
  auto stage = [&](int buf, int jt) {
    const int j0 = jt * 16;
    #pragma unroll
    for (int ii = 0; ii < 2; ++ii) {
      const int instr = 2 * w + ii;               // 0..7
      const int row = 2 * instr + (lane >> 5);    // 0..15
      const int gr = min(j0 + row, N - 1);
      const int sc16 = (lane & 31) ^ (row & 7);   // swizzled 16B chunk
      const size_t so = (size_t)gr * H + sc16 * 4;
      float* dst = &lds[buf][instr * 256];
      __builtin_amdgcn_global_load_lds(
          (const __attribute__((address_space(1))) void*)(eg + so),
          (__attribute__((address_space(3))) void*)dst, 16, 0, 0);
      __builtin_amdgcn_global_load_lds(
          (const __attribute__((address_space(1))) void*)(vxg + so),
          (__attribute__((address_space(3))) void*)(dst + 2048), 16, 0, 0);
      __builtin_amdgcn_global_load_lds(
          (const __attribute__((address_space(1))) void*)(vng + so),
          (__attribute__((address_space(3))) void*)(dst + 4096), 16, 0, 0);
    }
  };

  // ---- register prologue (all VMEM drained before the pipeline starts) ----
  if (tid < N) mrow[tid] = (float)mask[b * N + tid];

  short8 Wf[2][4];   // A-operand: lane holds W[hbase+ht*16+l15][s*32 + lg*8 + 0..7]
  #pragma unroll
  for (int ht = 0; ht < 2; ++ht) {
    const float* wr = &UeW[(size_t)(hbase + ht * 16 + l15) * H + lg * 8];
    #pragma unroll
    for (int s = 0; s < 4; ++s) {
      const f32x4 u0 = *(const f32x4*)(wr + s * 32);
      const f32x4 u1 = *(const f32x4*)(wr + s * 32 + 4);
      Wf[ht][s] = pack8(u0, u1);
    }
  }
  f32x4 base4[2];    // Ueb + Vx_i at lane's 4 consecutive h
  #pragma unroll
  for (int ht = 0; ht < 2; ++ht) {
    const int h0 = hbase + ht * 16 + 4 * lg;
    const f32x4 ub = *(const f32x4*)&Ueb[h0];
    const f32x4 vx = *(const f32x4*)&ws[WS_VX + (size_t)bi * H + h0];
    base4[ht] = ub + vx;
  }

  asm volatile("s_waitcnt vmcnt(0) lgkmcnt(0)" ::: "memory");
  __builtin_amdgcn_s_barrier();     // mrow visible; vmcnt clean

  stage(0, 0);                       // queue: S0(6)
  stage(1, 1);                       // queue: S0(6) S1(6)

  float bnS[2][4] = {{0,0,0,0},{0,0,0,0}};
  float bnS2[2][4] = {{0,0,0,0},{0,0,0,0}};
  float ag[2][4] = {{0,0,0,0},{0,0,0,0}};

  for (int jt = 0; jt < 13; ++jt) {
    // queue at top: S_jt(<=6) + S_{jt+1}(6) -> drain S_jt, keep S_{jt+1} in flight
    if (jt < 12) asm volatile("s_waitcnt vmcnt(6)" ::: "memory");
    else         asm volatile("s_waitcnt vmcnt(0)" ::: "memory");  // last: only S12 left
    __builtin_amdgcn_s_barrier();    // all waves' stage(jt) landed

    const float* tp = &lds[jt & 1][0];
    short8 Ef[4];                    // B-operand: col j = l15, k = lg*8 + s*32 + 0..7
    #pragma unroll
    for (int s = 0; s < 4; ++s) {
      const int c0 = (lg * 2 + s * 8) ^ (l15 & 7);
      const int c1 = (lg * 2 + s * 8 + 1) ^ (l15 & 7);
      const f32x4 u0 = *(const f32x4*)&tp[l15 * 128 + c0 * 4];
      const f32x4 u1 = *(const f32x4*)&tp[l15 * 128 + c1 * 4];
      Ef[s] = pack8(u0, u1);
    }
    f32x4 vx4[2], vn4[2];
    #pragma unroll
    for (int ht = 0; ht < 2; ++ht) {
      const int h0 = hbase + ht * 16 + 4 * lg;
      const int ch = (h0 >> 2) ^ (l15 & 7);
      vx4[ht] = *(const f32x4*)&tp[2048 + l15 * 128 + ch * 4];
      vn4[ht] = *(const f32x4*)&tp[4096 + l15 * 128 + ch * 4];
    }

    asm volatile("s_waitcnt lgkmcnt(0)" ::: "memory");
    __builtin_amdgcn_sched_barrier(0);
    __builtin_amdgcn_s_barrier();    // all waves done reading lds[jt&1]

    if (jt + 2 < 13) stage(jt & 1, jt + 2);   // overwrite freed buffer; waited 2 iters later

    f32x4 acc[2] = {f32x4(0.f), f32x4(0.f)};
    #pragma unroll
    for (int s = 0; s < 4; ++s) {
      #pragma unroll
      for (int ht = 0; ht < 2; ++ht)   // D[h][j]: col j = l15, row h = hbase+ht*16+4*lg+r
        acc[ht] = __builtin_amdgcn_mfma_f32_16x16x32_bf16(Wf[ht][s], Ef[s], acc[ht], 0, 0, 0);
    }

    // epilogue: registers only
    const int j = jt * 16 + l15;
    const float msk = (j < N) ? mi * mrow[j < N ? j : 0] : 0.f;
    #pragma unroll
    for (int ht = 0; ht < 2; ++ht) {
      #pragma unroll
      for (int r = 0; r < 4; ++r) {
        const float v = acc[ht][r] + base4[ht][r] + vx4[ht][r];
        bnS[ht][r]  += msk * v;
        bnS2[ht][r] += msk * v * v;
        const float sg = __builtin_amdgcn_rcpf(1.f + __expf(-v));
        ag[ht][r] += msk * sg * vn4[ht][r];
      }
    }
  }

  // reduce stats over j-lanes (l15: xor 1,2,4,8), then one writer per h
  #pragma unroll
  for (int ht = 0; ht < 2; ++ht) {
    #pragma unroll
    for (int r = 0; r < 4; ++r) {
      #pragma unroll
      for (int mm = 1; mm <= 8; mm <<= 1) {
        bnS[ht][r]  += __shfl_xor(bnS[ht][r], mm);
        bnS2[ht][r] += __shfl_xor(bnS2[ht][r], mm);
        ag[ht][r]   += __shfl_xor(ag[ht][r], mm);
      }
    }
  }
  if (l15 == 0) {
    #pragma unroll
    for (int ht = 0; ht < 2; ++ht) {
      #pragma unroll
      for (int r = 0; r < 4; ++r) {
        const int h = hbase + ht * 16 + 4 * lg + r;   // disjoint across writers
        sS[h] = bnS[ht][r]; sS2[h] = bnS2[ht][r]; sA[h] = ag[ht][r];
      }
    }
  }
  __syncthreads();
  if (tid < H) {
    const int slot = (bi & 31) * H + tid;
    atomicAdd(&ws[WS_ESUMS + slot], sS[tid]);
    atomicAdd(&ws[WS_ESSQS + slot], sS2[tid]);
    // fused x_tmp = Ux + agg, plus node BN partials
    const float v = ws[WS_UX + (size_t)bi * H + tid] + sA[tid];
    ws[WS_XTMP + (size_t)bi * H + tid] = v;
    atomicAdd(&ws[WS_NSUMS + slot], mi * v);
    atomicAdd(&ws[WS_NSSQS + slot], mi * v * v);
  }
}

// ---- counts + finalize BN scale/shift for edge and node ----
__global__ void k_stats(const int* __restrict__ mask,
                        const float* __restrict__ beg, const float* __restrict__ beb,
                        const float* __restrict__ bng, const float* __restrict__ bnb,
                        float* __restrict__ ws) {
  __shared__ float sb[8];
  const int t = threadIdx.x;          // 256 threads
  const int b = t >> 5, li = t & 31;
  float s = 0.f;
  for (int i = li; i < N; i += 32) s += (float)mask[b * N + i];
  #pragma unroll
  for (int o = 16; o >= 1; o >>= 1) s += __shfl_down(s, o, 32);
  if (li == 0) sb[b] = s;
  __syncthreads();
  if (t < H) {
    float cn = 0.f, ce = 0.f;
    #pragma unroll
    for (int bb = 0; bb < 8; ++bb) { cn += sb[bb]; ce += sb[bb] * sb[bb]; }
    ce = fmaxf(ce, 1.f); cn = fmaxf(cn, 1.f);
    float es = 0.f, es2 = 0.f, ns = 0.f, ns2 = 0.f;
    #pragma unroll 4
    for (int k = 0; k < 32; ++k) {
      es  += ws[WS_ESUMS + k * H + t];
      es2 += ws[WS_ESSQS + k * H + t];
      ns  += ws[WS_NSUMS + k * H + t];
      ns2 += ws[WS_NSSQS + k * H + t];
    }
    const float me = es / ce;
    const float ve = fmaxf(es2 / ce - me * me, 0.f);
    const float se = rsqrtf(ve + 1e-5f) * beg[t];
    ws[WS_ESC + t] = se;
    ws[WS_ESH + t] = beb[t] - me * se;
    const float mn = ns / cn;
    const float vn = fmaxf(ns2 / cn - mn * mn, 0.f);
    const float sn = rsqrtf(vn + 1e-5f) * bng[t];
    ws[WS_NSC + t] = sn;
    ws[WS_NSH + t] = bnb[t] - mn * sn;
  }
}

// ---- x_new = x + relu(masked BN(x_tmp)) ----
__global__ void k_x2(const float* __restrict__ x, const int* __restrict__ mask,
                     const float* __restrict__ ws, float* __restrict__ out) {
  const int idx = blockIdx.x * 256 + threadIdx.x;
  if (idx >= X_SIZE) return;
  const int h = idx & 127, bi = idx >> 7;
  const float v = ws[WS_XTMP + idx];
  const float r = (mask[bi] != 0) ? (v * ws[WS_NSC + h] + ws[WS_NSH + h]) : v;
  out[idx] = x[idx] + fmaxf(r, 0.f);
}

// ---- pass 1: recompute e_tmp, normalize + residual + write ----
// Counted-vmcnt pipeline with 4 loads/stage + 2 stores/iter. The top-of-loop
// waits are PEELED to match the exact per-wave VMEM issue history (round-7 bug:
// vmcnt(8) at jt=0 was a no-op since only 8 ops were outstanding -> race):
//   jt=0 : queue [S0(4) S1(4)]                         -> vmcnt(4) drains S0
//   jt=1 : queue [S1(4) S2(4) st0(2)]                  -> vmcnt(6) drains S1
//   jt>=2: queue [st(jt-3) S_jt st(jt-2) S_(jt+1) st(jt-1)] = 14
//                                                      -> vmcnt(8) drains S_jt
//   jt=12: queue [st9(2) S12(4) st10(2) st11(2)]       -> vmcnt(4) drains S12
__global__ __launch_bounds__(256, 3) void k_edge1(
    const float* __restrict__ e, const int* __restrict__ mask,
    const float* __restrict__ UeW, const float* __restrict__ Ueb,
    const float* __restrict__ ws, float* __restrict__ out) {
  const int bi = blockIdx.x;
  const int b = bi / N;
  const int tid = threadIdx.x;
  const int w = tid >> 6, lane = tid & 63;
  const int l15 = lane & 15, lg = lane >> 4;
  const int hbase = w * 32;

  __shared__ float lds[2][2 * 2048];   // [buf][e | vx], 32 KB
  __shared__ float mrow[N];

  const float mi = (float)mask[bi];
  const float* __restrict__ eg  = e + (size_t)bi * NH;
  const float* __restrict__ vxg = ws + WS_VX + (size_t)b * NH;

  auto stage = [&](int buf, int jt) {
    const int j0 = jt * 16;
    #pragma unroll
    for (int ii = 0; ii < 2; ++ii) {
      const int instr = 2 * w + ii;
      const int row = 2 * instr + (lane >> 5);
      const int gr = min(j0 + row, N - 1);
      const int sc16 = (lane & 31) ^ (row & 7);
      const size_t so = (size_t)gr * H + sc16 * 4;
      float* dst = &lds[buf][instr * 256];
      __builtin_amdgcn_global_load_lds(
          (const __attribute__((address_space(1))) void*)(eg + so),
          (__attribute__((address_space(3))) void*)dst, 16, 0, 0);
      __builtin_amdgcn_global_load_lds(
          (const __attribute__((address_space(1))) void*)(vxg + so),
          (__attribute__((address_space(3))) void*)(dst + 2048), 16, 0, 0);
    }
  };

  // ---- register prologue ----
  if (tid < N) mrow[tid] = (float)mask[b * N + tid];

  short8 Wf[2][4];
  #pragma unroll
  for (int ht = 0; ht < 2; ++ht) {
    const float* wr = &UeW[(size_t)(hbase + ht * 16 + l15) * H + lg * 8];
    #pragma unroll
    for (int s = 0; s < 4; ++s) {
      const f32x4 u0 = *(const f32x4*)(wr + s * 32);
      const f32x4 u1 = *(const f32x4*)(wr + s * 32 + 4);
      Wf[ht][s] = pack8(u0, u1);
    }
  }
  f32x4 base4[2], sc4[2], sh4[2];
  #pragma unroll
  for (int ht = 0; ht < 2; ++ht) {
    const int h0 = hbase + ht * 16 + 4 * lg;
    const f32x4 ub = *(const f32x4*)&Ueb[h0];
    const f32x4 vx = *(const f32x4*)&ws[WS_VX + (size_t)bi * H + h0];
    base4[ht] = ub + vx;
    sc4[ht] = *(const f32x4*)&ws[WS_ESC + h0];
    sh4[ht] = *(const f32x4*)&ws[WS_ESH + h0];
  }

  asm volatile("s_waitcnt vmcnt(0) lgkmcnt(0)" ::: "memory");
  __builtin_amdgcn_s_barrier();

  stage(0, 0);
  stage(1, 1);

  for (int jt = 0; jt < 13; ++jt) {
    if (jt == 0)      asm volatile("s_waitcnt vmcnt(4)" ::: "memory");
    else if (jt == 1) asm volatile("s_waitcnt vmcnt(6)" ::: "memory");
    else if (jt < 12) asm volatile("s_waitcnt vmcnt(8)" ::: "memory");
    else              asm volatile("s_waitcnt vmcnt(4)" ::: "memory");
    __builtin_amdgcn_s_barrier();

    const float* tp = &lds[jt & 1][0];
    short8 Ef[4];
    #pragma unroll
    for (int s = 0; s < 4; ++s) {
      const int c0 = (lg * 2 + s * 8) ^ (l15 & 7);
      const int c1 = (lg * 2 + s * 8 + 1) ^ (l15 & 7);
      const f32x4 u0 = *(const f32x4*)&tp[l15 * 128 + c0 * 4];
      const f32x4 u1 = *(const f32x4*)&tp[l15 * 128 + c1 * 4];
      Ef[s] = pack8(u0, u1);
    }
    f32x4 vx4[2], e4[2];
    #pragma unroll
    for (int ht = 0; ht < 2; ++ht) {
      const int h0 = hbase + ht * 16 + 4 * lg;
      const int ch = (h0 >> 2) ^ (l15 & 7);
      vx4[ht] = *(const f32x4*)&tp[2048 + l15 * 128 + ch * 4];
      e4[ht]  = *(const f32x4*)&tp[l15 * 128 + ch * 4];   // residual
    }

    asm volatile("s_waitcnt lgkmcnt(0)" ::: "memory");
    __builtin_amdgcn_sched_barrier(0);
    __builtin_amdgcn_s_barrier();

    if (jt + 2 < 13) stage(jt & 1, jt + 2);

    f32x4 acc[2] = {f32x4(0.f), f32x4(0.f)};
    #pragma unroll
    for (int s = 0; s < 4; ++s) {
      #pragma unroll
      for (int ht = 0; ht < 2; ++ht)
        acc[ht] = __builtin_amdgcn_mfma_f32_16x16x32_bf16(Wf[ht][s], Ef[s], acc[ht], 0, 0, 0);
    }

    const int j = jt * 16 + l15;
    if (j < N) {
      const float msk = mi * mrow[j];
      float* __restrict__ og = out + (size_t)X_SIZE + (size_t)bi * NH + (size_t)j * H;
      #pragma unroll
      for (int ht = 0; ht < 2; ++ht) {
        const int h0 = hbase + ht * 16 + 4 * lg;
        f32x4 o;
        #pragma unroll
        for (int r = 0; r < 4; ++r) {
          const float v = acc[ht][r] + base4[ht][r] + vx4[ht][r];
          const float rr = (msk > 0.f) ? (v * sc4[ht][r] + sh4[ht][r]) : v;
          o[r] = e4[ht][r] + fmaxf(rr, 0.f);
        }
        *(f32x4*)&og[h0] = o;
      }
    }
  }
}

}  // namespace

extern "C" void kernel_launch(void* const* d_in, const int* in_sizes, int n_in,
                              void* d_out, int out_size, void* d_ws, size_t ws_size,
                              hipStream_t stream) {
  const float* x    = (const float*)d_in[0];
  const float* e    = (const float*)d_in[1];
  const int*   mask = (const int*)d_in[2];
  const float* UeW  = (const float*)d_in[3];
  const float* Ueb  = (const float*)d_in[4];
  const float* VeW  = (const float*)d_in[5];
  const float* Veb  = (const float*)d_in[6];
  const float* UnW  = (const float*)d_in[7];
  const float* Unb  = (const float*)d_in[8];
  const float* VnW  = (const float*)d_in[9];
  const float* Vnb  = (const float*)d_in[10];
  const float* bng  = (const float*)d_in[11];
  const float* bnb  = (const float*)d_in[12];
  const float* beg  = (const float*)d_in[13];
  const float* beb  = (const float*)d_in[14];
  float* ws  = (float*)d_ws;
  float* out = (float*)d_out;

  // zero the slotted stat accumulators (contiguous 4 x 32 x H region)
  hipMemsetAsync(ws + WS_ESUMS, 0, (WS_STAT_END - WS_ESUMS) * sizeof(float), stream);
  k_prep<<<BN, 128, 0, stream>>>(x, mask, VeW, Veb, UnW, Unb, VnW, Vnb, ws);
  k_edge0<<<BN, 256, 0, stream>>>(e, mask, UeW, Ueb, ws);
  k_stats<<<1, 256, 0, stream>>>(mask, beg, beb, bng, bnb, ws);
  k_x2<<<800, 256, 0, stream>>>(x, mask, ws, out);
  k_edge1<<<BN, 256, 0, stream>>>(e, mask, UeW, Ueb, ws, out);
}